// Round 2
// baseline (1077.058 us; speedup 1.0000x reference)
//
#include <hip/hip_runtime.h>

#define D_MODEL  2048
#define N_EXP    64
#define KQUADS   (D_MODEL / 4)   // 512
#define T_PER_WAVE 16

// ---- repack W[64][2048] -> Wq[kq][e][i] (i = k within quad), 131072 floats --
__global__ void make_Wq(const float* __restrict__ W, float* __restrict__ Wq) {
    int o  = blockIdx.x * 256 + threadIdx.x;   // coalesced write
    int i  = o & 3;
    int e  = (o >> 2) & 63;
    int kq = o >> 8;
    Wq[o] = W[e * D_MODEL + 4 * kq + i];
}

// ---- main router: lane = expert, 16 tokens per wave, no LDS ----------------
__global__ __launch_bounds__(256)
void router_b(const float* __restrict__ x,
              const float* __restrict__ Wq,
              const float* __restrict__ bias,
              float* __restrict__ out,
              int n_tokens)
{
    const int tid  = threadIdx.x;
    const int lane = tid & 63;
    const int wv   = __builtin_amdgcn_readfirstlane(tid >> 6);  // force wave-uniform
    const int tok0 = blockIdx.x * (4 * T_PER_WAVE) + wv * T_PER_WAVE;

    const float4* __restrict__ Wq4  = (const float4*)Wq;
    const float4* __restrict__ xrow = (const float4*)(x + (size_t)tok0 * D_MODEL); // uniform base

    float acc[T_PER_WAVE];
    #pragma unroll
    for (int t = 0; t < T_PER_WAVE; ++t) acc[t] = 0.f;

    #pragma unroll 2
    for (int kq = 0; kq < KQUADS; ++kq) {
        const float4 w = Wq4[(size_t)kq * N_EXP + lane];   // coalesced, L2-resident
        #pragma unroll
        for (int t = 0; t < T_PER_WAVE; ++t) {
            const float4 xv = xrow[(size_t)t * KQUADS + kq];  // uniform -> s_load_dwordx4
            acc[t] = fmaf(xv.x, w.x, acc[t]);
            acc[t] = fmaf(xv.y, w.y, acc[t]);
            acc[t] = fmaf(xv.z, w.z, acc[t]);
            acc[t] = fmaf(xv.w, w.w, acc[t]);
        }
    }

    const float bl = bias[lane];
    float* ow = out + 2 * (size_t)n_tokens;

    #pragma unroll
    for (int t = 0; t < T_PER_WAVE; ++t) {
        const float v = acc[t] + bl;     // this lane's logit for expert `lane`
        // ---- cross-lane top-2 butterfly (tie: lower index wins) ----
        float v1 = v;      int i1 = lane;
        float v2 = -3.4e38f; int i2 = 64;
        #pragma unroll
        for (int m = 1; m < 64; m <<= 1) {
            float b1 = __shfl_xor(v1, m, 64); int j1 = __shfl_xor(i1, m, 64);
            float b2 = __shfl_xor(v2, m, 64); int j2 = __shfl_xor(i2, m, 64);
            bool aw = (v1 > b1) || (v1 == b1 && i1 < j1);
            float lw_v = aw ? b1 : v1;  int lw_i = aw ? j1 : i1;   // loser of firsts
            float ws_v = aw ? v2 : b2;  int ws_i = aw ? i2 : j2;   // winner's second
            float nv1  = aw ? v1 : b1;  int ni1  = aw ? i1 : j1;
            bool sw = (lw_v > ws_v) || (lw_v == ws_v && lw_i < ws_i);
            v1 = nv1;                i1 = ni1;
            v2 = sw ? lw_v : ws_v;   i2 = sw ? lw_i : ws_i;
        }
        // ---- softmax weights: sum exp(v - v1) over all 64 lanes ----
        float s = __expf(v - v1);
        #pragma unroll
        for (int m = 1; m < 64; m <<= 1) s += __shfl_xor(s, m, 64);
        const float inv = 1.0f / s;
        const float w1  = inv;                    // exp(v1-v1)/s
        const float w2  = __expf(v2 - v1) * inv;

        if (lane == t) {
            const int g = tok0 + t;
            float2 fi; fi.x = (float)i1; fi.y = (float)i2;
            ((float2*)out)[g] = fi;               // idx chunk (as float32 values)
            float2 fw; fw.x = w1; fw.y = w2;
            ((float2*)ow)[g] = fw;                // weight chunk
        }
    }
}

extern "C" void kernel_launch(void* const* d_in, const int* in_sizes, int n_in,
                              void* d_out, int out_size, void* d_ws, size_t ws_size,
                              hipStream_t stream) {
    const float* x = (const float*)d_in[0];
    const float* W = (const float*)d_in[1];
    const float* b = (const float*)d_in[2];
    float* out = (float*)d_out;
    float* Wq  = (float*)d_ws;                       // 512 KB scratch
    const int n_tokens = in_sizes[0] / D_MODEL;      // 32768

    make_Wq<<<(D_MODEL * N_EXP) / 256, 256, 0, stream>>>(W, Wq);
    const int tokens_per_block = 4 * T_PER_WAVE;     // 64
    router_b<<<n_tokens / tokens_per_block, 256, 0, stream>>>(x, Wq, b, out, n_tokens);
}

// Round 3
// 856.946 us; speedup vs baseline: 1.2569x; 1.2569x over previous
//
#include <hip/hip_runtime.h>

#define D_MODEL 2048
#define N_EXP   64
#define TOKS_PER_BLOCK 64
#define WAVES   8                       // 512 threads
#define K_PER_WAVE (D_MODEL / WAVES)    // 256
#define KS      16                      // k per super-step
#define NSUP    (K_PER_WAVE / KS)       // 16
#define XS_ROW_F4  5                    // 4 data float4 + 1 pad (banks: 5*tg mod 8 covers all quads)
#define XS_WAVE_F4 (64 * XS_ROW_F4)     // 320 float4 = 5120 B per wave

// ---- W repack: Wq2[kq][j][eg] = float4{ W[8j+eg][4kq+i] } ------------------
__global__ void make_Wq2(const float* __restrict__ W, float* __restrict__ Wq2) {
    int o  = blockIdx.x * 256 + threadIdx.x;  // element over 2048*64
    int i  = o & 3;
    int eg = (o >> 2) & 7;
    int j  = (o >> 5) & 7;
    int kq = o >> 8;
    Wq2[o] = W[(8 * j + eg) * D_MODEL + 4 * kq + i];
}

union SMemU {
    float4 xs[WAVES * XS_WAVE_F4];      // 40960 B
    float  red[4 * 32 * 65];            // 33280 B (half-token reduction buffers)
};

__global__ __launch_bounds__(512, 4)
void router_c(const float* __restrict__ x, const float4* __restrict__ Wq2,
              const float* __restrict__ bias, float* __restrict__ out, int n_tokens)
{
    __shared__ SMemU sm;
    const int tid  = threadIdx.x;
    const int lane = tid & 63;
    const int wv   = tid >> 6;
    const int tg   = lane >> 3;       // token group: lane handles tokens 8*tt + tg
    const int eg   = lane & 7;        // expert group: lane handles experts 8*j + eg
    const int tok0 = blockIdx.x * TOKS_PER_BLOCK;
    const int kw   = wv * K_PER_WAVE; // this wave's private K range

    float acc[8][8];
    #pragma unroll
    for (int tt = 0; tt < 8; ++tt)
        #pragma unroll
        for (int j = 0; j < 8; ++j) acc[tt][j] = 0.f;

    float4* xw = sm.xs + wv * XS_WAVE_F4;   // per-wave private region -> no barriers

    for (int s = 0; s < NSUP; ++s) {
        const int kb = kw + s * KS;
        // ---- stage 64 tokens x 16 k into private LDS (4 float4 per lane) ----
        float4 stg[4];
        #pragma unroll
        for (int i = 0; i < 4; ++i) {
            const int t = i * 16 + (lane >> 2);
            const int c = lane & 3;
            stg[i] = *(const float4*)(x + (size_t)(tok0 + t) * D_MODEL + kb + 4 * c);
        }
        #pragma unroll
        for (int i = 0; i < 4; ++i) {
            const int t = i * 16 + (lane >> 2);
            const int c = lane & 3;
            xw[XS_ROW_F4 * t + c] = stg[i];
        }
        // ---- compute: 4 kq x (8 ds_read + 8 W-load + 256 FMA) ---------------
        #pragma unroll
        for (int q = 0; q < KS / 4; ++q) {
            const int kq = (kb >> 2) + q;
            float4 xv[8];
            #pragma unroll
            for (int tt = 0; tt < 8; ++tt)
                xv[tt] = xw[XS_ROW_F4 * (8 * tt + tg) + q];   // 8-way broadcast, quad-spread
            const float4* wp = Wq2 + (size_t)kq * 64 + eg;
            #pragma unroll
            for (int j = 0; j < 8; ++j) {
                const float4 w4 = wp[8 * j];                  // 128B contiguous per instr
                #pragma unroll
                for (int tt = 0; tt < 8; ++tt) {
                    acc[tt][j] = fmaf(w4.x, xv[tt].x, acc[tt][j]);
                    acc[tt][j] = fmaf(w4.y, xv[tt].y, acc[tt][j]);
                    acc[tt][j] = fmaf(w4.z, xv[tt].z, acc[tt][j]);
                    acc[tt][j] = fmaf(w4.w, xv[tt].w, acc[tt][j]);
                }
            }
        }
    }

    // ---- cross-wave reduction: 8 partials -> wave 0, in 2 token-halves ------
    __syncthreads();
    for (int h = 0; h < 2; ++h) {
        if (wv >= 4) {
            float* R = sm.red + (size_t)(wv - 4) * (32 * 65);
            #pragma unroll
            for (int tt2 = 0; tt2 < 4; ++tt2)
                #pragma unroll
                for (int j = 0; j < 8; ++j)
                    R[(8 * tt2 + tg) * 65 + 8 * j + eg] = acc[4 * h + tt2][j];
        }
        __syncthreads();
        if (wv < 4) {
            const float* R = sm.red + (size_t)wv * (32 * 65);
            #pragma unroll
            for (int tt2 = 0; tt2 < 4; ++tt2)
                #pragma unroll
                for (int j = 0; j < 8; ++j)
                    acc[4 * h + tt2][j] += R[(8 * tt2 + tg) * 65 + 8 * j + eg];
        }
        __syncthreads();
        if (wv == 2 || wv == 3) {
            float* R = sm.red + (size_t)(wv - 2) * (32 * 65);
            #pragma unroll
            for (int tt2 = 0; tt2 < 4; ++tt2)
                #pragma unroll
                for (int j = 0; j < 8; ++j)
                    R[(8 * tt2 + tg) * 65 + 8 * j + eg] = acc[4 * h + tt2][j];
        }
        __syncthreads();
        if (wv < 2) {
            const float* R = sm.red + (size_t)wv * (32 * 65);
            #pragma unroll
            for (int tt2 = 0; tt2 < 4; ++tt2)
                #pragma unroll
                for (int j = 0; j < 8; ++j)
                    acc[4 * h + tt2][j] += R[(8 * tt2 + tg) * 65 + 8 * j + eg];
        }
        __syncthreads();
        if (wv == 1) {
            float* R = sm.red;
            #pragma unroll
            for (int tt2 = 0; tt2 < 4; ++tt2)
                #pragma unroll
                for (int j = 0; j < 8; ++j)
                    R[(8 * tt2 + tg) * 65 + 8 * j + eg] = acc[4 * h + tt2][j];
        }
        __syncthreads();
        if (wv == 0) {
            const float* R = sm.red;
            #pragma unroll
            for (int tt2 = 0; tt2 < 4; ++tt2)
                #pragma unroll
                for (int j = 0; j < 8; ++j)
                    acc[4 * h + tt2][j] += R[(8 * tt2 + tg) * 65 + 8 * j + eg];
        }
        __syncthreads();   // buffers reused next half
    }

    // ---- epilogue: bias + top-2 + softmax, wave 0 only ----------------------
    if (wv == 0) {
        float bj[8];
        #pragma unroll
        for (int j = 0; j < 8; ++j) bj[j] = bias[8 * j + eg];
        float* ow = out + 2 * (size_t)n_tokens;

        #pragma unroll
        for (int tt = 0; tt < 8; ++tt) {
            float v[8];
            #pragma unroll
            for (int j = 0; j < 8; ++j) v[j] = acc[tt][j] + bj[j];
            // local top-2 over this lane's 8 experts (e = 8j+eg, ascending, strict >)
            float v1 = v[0]; int i1 = eg;
            float v2 = -3.4e38f; int i2 = 1 << 20;
            #pragma unroll
            for (int j = 1; j < 8; ++j) {
                const int e = 8 * j + eg;
                if (v[j] > v1)      { v2 = v1; i2 = i1; v1 = v[j]; i1 = e; }
                else if (v[j] > v2) { v2 = v[j]; i2 = e; }
            }
            // butterfly merge across the 8 eg-lanes of this tg group
            #pragma unroll
            for (int m = 1; m < 8; m <<= 1) {
                float b1 = __shfl_xor(v1, m, 64); int j1 = __shfl_xor(i1, m, 64);
                float b2 = __shfl_xor(v2, m, 64); int j2 = __shfl_xor(i2, m, 64);
                bool aw = (v1 > b1) || (v1 == b1 && i1 < j1);
                float lw_v = aw ? b1 : v1;  int lw_i = aw ? j1 : i1;
                float ws_v = aw ? v2 : b2;  int ws_i = aw ? i2 : j2;
                float nv1  = aw ? v1 : b1;  int ni1  = aw ? i1 : j1;
                bool sw = (lw_v > ws_v) || (lw_v == ws_v && lw_i < ws_i);
                v1 = nv1;               i1 = ni1;
                v2 = sw ? lw_v : ws_v;  i2 = sw ? lw_i : ws_i;
            }
            // softmax denominator over all 64 experts
            float ssum = 0.f;
            #pragma unroll
            for (int j = 0; j < 8; ++j) ssum += __expf(v[j] - v1);
            #pragma unroll
            for (int m = 1; m < 8; m <<= 1) ssum += __shfl_xor(ssum, m, 64);
            const float inv = 1.0f / ssum;
            const float w1  = inv;
            const float w2  = __expf(v2 - v1) * inv;

            if (eg == tt) {
                const int g = tok0 + 8 * tt + tg;
                float2 fi; fi.x = (float)i1; fi.y = (float)i2;
                ((float2*)out)[g] = fi;
                float2 fw; fw.x = w1; fw.y = w2;
                ((float2*)ow)[g] = fw;
            }
        }
    }
}

extern "C" void kernel_launch(void* const* d_in, const int* in_sizes, int n_in,
                              void* d_out, int out_size, void* d_ws, size_t ws_size,
                              hipStream_t stream) {
    const float* x = (const float*)d_in[0];
    const float* W = (const float*)d_in[1];
    const float* b = (const float*)d_in[2];
    float* out = (float*)d_out;
    float* Wq2 = (float*)d_ws;                       // 512 KB scratch
    const int n_tokens = in_sizes[0] / D_MODEL;      // 32768

    make_Wq2<<<(D_MODEL * N_EXP) / 256, 256, 0, stream>>>(W, Wq2);
    router_c<<<n_tokens / TOKS_PER_BLOCK, 512, 0, stream>>>(x, (const float4*)Wq2, b, out, n_tokens);
}

// Round 4
// 488.191 us; speedup vs baseline: 2.2062x; 1.7554x over previous
//
#include <hip/hip_runtime.h>
#include <stdint.h>

#define D_MODEL 2048
#define N_EXP   64
#define TOKS    32                  // tokens per block
#define WAVES   4                   // 256 threads
#define KW      (D_MODEL / WAVES)   // 512 k per wave (private K-split)
#define KS      64                  // k per stage
#define NS      (KW / KS)           // 8 stages
#define ROW_F4  16                  // 64 k = 16 float4 per token row (NO pad; XOR swizzle)

// ---- W repack: Wq2[kq][j][eg] = float4{ W[8j+eg][4kq+i] }, 512 KB in d_ws --
__global__ void make_Wq2(const float* __restrict__ W, float* __restrict__ Wq2) {
    int o  = blockIdx.x * 256 + threadIdx.x;
    int i  = o & 3;
    int eg = (o >> 2) & 7;
    int j  = (o >> 5) & 7;
    int kq = o >> 8;
    Wq2[o] = W[(8 * j + eg) * D_MODEL + 4 * kq + i];
}

union SMemU {
    float4 xs[WAVES * TOKS * ROW_F4];   // 32768 B: per-wave-private staging
    float  red[2][TOKS * 65];           // 16640 B reduction overlay (pad 65)
};

__global__ __launch_bounds__(256, 4)
void router_d(const float* __restrict__ x, const float4* __restrict__ Wq2,
              const float* __restrict__ bias, float* __restrict__ out, int n_tokens)
{
    __shared__ SMemU sm;
    const int tid  = threadIdx.x;
    const int lane = tid & 63;
    const int wv   = tid >> 6;
    const int tg   = lane >> 3;       // token group: tokens t = 8*tt + tg
    const int eg   = lane & 7;        // expert group: experts e = 8*j + eg
    const int tok0 = blockIdx.x * TOKS;
    const int kw   = wv * KW;

    // staging lane decomposition: each instr covers 4 tokens x 16 float4
    const int trow = lane >> 4;       // 0..3
    const int c    = lane & 15;       // 0..15

    float acc[4][8];
    #pragma unroll
    for (int tt = 0; tt < 4; ++tt)
        #pragma unroll
        for (int j = 0; j < 8; ++j) acc[tt][j] = 0.f;

    float4* ldsbase = sm.xs + wv * (TOKS * ROW_F4);   // per-wave private: no barriers

    for (int s = 0; s < NS; ++s) {
        const int kb = kw + s * KS;
        // ---- async stage 32 tokens x 64 k, 8 x 1KB instrs, zero VGPR temps --
        #pragma unroll
        for (int it = 0; it < 8; ++it) {
            const int t  = 4 * it + trow;
            const int gc = c ^ (t & 7);                       // XOR swizzle column
            const float* gp = x + (size_t)(tok0 + t) * D_MODEL + kb + 4 * gc;
            float4* lp = ldsbase + it * 64;                   // wave-uniform base
            __builtin_amdgcn_global_load_lds(
                (const __attribute__((address_space(1))) void*)gp,
                (__attribute__((address_space(3))) void*)lp, 16, 0, 0);
        }
        asm volatile("s_waitcnt vmcnt(0)" ::: "memory");
        // ---- compute: 16 kq x (4 ds_read_b128 + 8 W float4 + 128 FMA) ------
        #pragma unroll
        for (int q = 0; q < KS / 4; ++q) {
            const int kq = (kb >> 2) + q;
            float4 xv[4];
            #pragma unroll
            for (int tt = 0; tt < 4; ++tt) {
                const int t = 8 * tt + tg;
                xv[tt] = ldsbase[(size_t)t * ROW_F4 + (q ^ tg)];  // conflict-free quads
            }
            const float4* wp = Wq2 + (size_t)kq * 64 + eg;
            #pragma unroll
            for (int j = 0; j < 8; ++j) {
                const float4 w4 = wp[8 * j];                  // 128B coalesced, L2-hit
                #pragma unroll
                for (int tt = 0; tt < 4; ++tt) {
                    acc[tt][j] = fmaf(w4.x, xv[tt].x, acc[tt][j]);
                    acc[tt][j] = fmaf(w4.y, xv[tt].y, acc[tt][j]);
                    acc[tt][j] = fmaf(w4.z, xv[tt].z, acc[tt][j]);
                    acc[tt][j] = fmaf(w4.w, xv[tt].w, acc[tt][j]);
                }
            }
        }
    }

    // ---- cross-wave reduction: 4 K-partials -> wave 0 -----------------------
    __syncthreads();                      // staging dead; overlay becomes live
    if (wv >= 2) {
        float* R = sm.red[wv - 2];
        #pragma unroll
        for (int tt = 0; tt < 4; ++tt)
            #pragma unroll
            for (int j = 0; j < 8; ++j)
                R[(8 * tt + tg) * 65 + 8 * j + eg] = acc[tt][j];
    }
    __syncthreads();
    if (wv < 2) {
        const float* R = sm.red[wv];
        #pragma unroll
        for (int tt = 0; tt < 4; ++tt)
            #pragma unroll
            for (int j = 0; j < 8; ++j)
                acc[tt][j] += R[(8 * tt + tg) * 65 + 8 * j + eg];
    }
    __syncthreads();
    if (wv == 1) {
        float* R = sm.red[0];
        #pragma unroll
        for (int tt = 0; tt < 4; ++tt)
            #pragma unroll
            for (int j = 0; j < 8; ++j)
                R[(8 * tt + tg) * 65 + 8 * j + eg] = acc[tt][j];
    }
    __syncthreads();

    // ---- epilogue: bias + top-2 + softmax, wave 0 ---------------------------
    if (wv == 0) {
        const float* R = sm.red[0];
        float bj[8];
        #pragma unroll
        for (int j = 0; j < 8; ++j) bj[j] = bias[8 * j + eg];
        float* ow = out + 2 * (size_t)n_tokens;

        #pragma unroll
        for (int tt = 0; tt < 4; ++tt) {
            float v[8];
            #pragma unroll
            for (int j = 0; j < 8; ++j)
                v[j] = acc[tt][j] + R[(8 * tt + tg) * 65 + 8 * j + eg] + bj[j];
            // local top-2 over this lane's 8 experts (e = 8j+eg ascending)
            float v1 = v[0]; int i1 = eg;
            float v2 = -3.4e38f; int i2 = 1 << 20;
            #pragma unroll
            for (int j = 1; j < 8; ++j) {
                const int e = 8 * j + eg;
                if (v[j] > v1)      { v2 = v1; i2 = i1; v1 = v[j]; i1 = e; }
                else if (v[j] > v2) { v2 = v[j]; i2 = e; }
            }
            // butterfly merge across the 8 eg-lanes (tie: lower index)
            #pragma unroll
            for (int m = 1; m < 8; m <<= 1) {
                float b1 = __shfl_xor(v1, m, 64); int j1 = __shfl_xor(i1, m, 64);
                float b2 = __shfl_xor(v2, m, 64); int j2 = __shfl_xor(i2, m, 64);
                bool aw = (v1 > b1) || (v1 == b1 && i1 < j1);
                float lw_v = aw ? b1 : v1;  int lw_i = aw ? j1 : i1;
                float ws_v = aw ? v2 : b2;  int ws_i = aw ? i2 : j2;
                float nv1  = aw ? v1 : b1;  int ni1  = aw ? i1 : j1;
                bool sw = (lw_v > ws_v) || (lw_v == ws_v && lw_i < ws_i);
                v1 = nv1;               i1 = ni1;
                v2 = sw ? lw_v : ws_v;  i2 = sw ? lw_i : ws_i;
            }
            // softmax denominator over all 64 experts
            float ssum = 0.f;
            #pragma unroll
            for (int j = 0; j < 8; ++j) ssum += __expf(v[j] - v1);
            #pragma unroll
            for (int m = 1; m < 8; m <<= 1) ssum += __shfl_xor(ssum, m, 64);
            const float inv = 1.0f / ssum;
            const float w1  = inv;
            const float w2  = __expf(v2 - v1) * inv;

            if (eg == tt) {
                const int g = tok0 + 8 * tt + tg;
                float2 fi; fi.x = (float)i1; fi.y = (float)i2;
                ((float2*)out)[g] = fi;
                float2 fw; fw.x = w1; fw.y = w2;
                ((float2*)ow)[g] = fw;
            }
        }
    }
}

extern "C" void kernel_launch(void* const* d_in, const int* in_sizes, int n_in,
                              void* d_out, int out_size, void* d_ws, size_t ws_size,
                              hipStream_t stream) {
    const float* x = (const float*)d_in[0];
    const float* W = (const float*)d_in[1];
    const float* b = (const float*)d_in[2];
    float* out = (float*)d_out;
    float* Wq2 = (float*)d_ws;                       // 512 KB scratch
    const int n_tokens = in_sizes[0] / D_MODEL;      // 32768

    make_Wq2<<<(D_MODEL * N_EXP) / 256, 256, 0, stream>>>(W, Wq2);
    router_d<<<n_tokens / TOKS, 256, 0, stream>>>(x, (const float4*)Wq2, b, out, n_tokens);
}